// Round 1
// baseline (585.738 us; speedup 1.0000x reference)
//
#include <hip/hip_runtime.h>
#include <hip/hip_bf16.h>
#include <cstdint>

#define HEADS 12
#define HEAD_SIZE 64
#define SEQ 512
#define HD 1024
#define NPROJ 1536   // HEADS * 2 * HEAD_SIZE
#define INF_VAL 1e13f

typedef __attribute__((ext_vector_type(8))) __bf16 bf16x8;
typedef __attribute__((ext_vector_type(4))) float f32x4;

__device__ __forceinline__ unsigned short f2bf(float f) {
    unsigned u = __float_as_uint(f);
    u += 0x7fffu + ((u >> 16) & 1u);   // RNE
    return (unsigned short)(u >> 16);
}

// async global -> LDS, 16B per lane, lane-ordered contiguous LDS destination
__device__ __forceinline__ void gl_lds16(const unsigned short* g, unsigned short* l) {
    __builtin_amdgcn_global_load_lds(
        (const __attribute__((address_space(1))) unsigned int*)g,
        (__attribute__((address_space(3))) unsigned int*)l, 16, 0, 0);
}

// ---------------------------------------------------------------------------
// Kernel 0: x (f32) -> xb (bf16), flat cast. 16,777,216 elems, 8 per thread.
// ---------------------------------------------------------------------------
__global__ void __launch_bounds__(256) convert_x(const float* __restrict__ x,
                                                 unsigned short* __restrict__ xb) {
    const int i = blockIdx.x * 256 + threadIdx.x;
    const float4* src = (const float4*)x;
    float4 v0 = src[i * 2 + 0];
    float4 v1 = src[i * 2 + 1];
    uint4 p;
    p.x = f2bf(v0.x) | ((unsigned)f2bf(v0.y) << 16);
    p.y = f2bf(v0.z) | ((unsigned)f2bf(v0.w) << 16);
    p.z = f2bf(v1.x) | ((unsigned)f2bf(v1.y) << 16);
    p.w = f2bf(v1.z) | ((unsigned)f2bf(v1.w) << 16);
    ((uint4*)xb)[i] = p;
}

// ---------------------------------------------------------------------------
// Kernel 1: W (1024 x 1536 f32, row-major) -> Wt (1536 x 1024 bf16)
// ---------------------------------------------------------------------------
__global__ void __launch_bounds__(256) transpose_cast_w(const float* __restrict__ W,
                                                        unsigned short* __restrict__ Wt) {
    __shared__ unsigned short tile[64][65];
    const int bx = blockIdx.x;
    const int k0 = (bx & 15) * 64;   // 16 k-tiles
    const int n0 = (bx >> 4) * 64;   // 24 n-tiles
    const int t = threadIdx.x;
    const int tr = t >> 4;           // 0..15
    const int tc = (t & 15) * 4;     // 0..60
#pragma unroll
    for (int i = 0; i < 4; ++i) {
        int kk = tr + i * 16;
        float4 v = *(const float4*)&W[(size_t)(k0 + kk) * NPROJ + n0 + tc];
        tile[kk][tc + 0] = f2bf(v.x);
        tile[kk][tc + 1] = f2bf(v.y);
        tile[kk][tc + 2] = f2bf(v.z);
        tile[kk][tc + 3] = f2bf(v.w);
    }
    __syncthreads();
#pragma unroll
    for (int i = 0; i < 4; ++i) {
        int nn = tr + i * 16;
        ushort4 o;
        o.x = tile[tc + 0][nn];
        o.y = tile[tc + 1][nn];
        o.z = tile[tc + 2][nn];
        o.w = tile[tc + 3][nn];
        *(ushort4*)&Wt[(size_t)(n0 + nn) * HD + k0 + tc] = o;
    }
}

// ---------------------------------------------------------------------------
// Kernel 1b: RoPE sin/cos table -> global, 512 positions x 32 freqs, f32x2.
// Built once (128 KB, L2-resident for gemm1's reads).
// ---------------------------------------------------------------------------
__global__ void __launch_bounds__(256) rope_table(float2* __restrict__ tab) {
    const int e = blockIdx.x * 256 + threadIdx.x;   // 0..16383
    const int srow = e >> 5;
    const int fi = e & 31;
    float invf = __expf(-(float)fi * (0.03125f * 9.210340371976184f)); // 10000^(-fi/32)
    float theta = (float)srow * invf;
    float sv, cv;
    __sincosf(theta, &sv, &cv);
    tab[e] = make_float2(sv, cv);
}

// ---------------------------------------------------------------------------
// Kernel 2: proj = xb @ Wt^T + b, fused RoPE, writes q/k bf16 in (B,H,S,D).
// m97 K-loop unchanged. NEW epilogue: RoPE table from global (no per-block
// sincos), v_cvt_pk_bf16_f32 pair packing, LDS-staged output tile
// (144B XOR-swizzled rows), fully-coalesced dwordx4 q/k stores.
// ---------------------------------------------------------------------------
__global__ void __launch_bounds__(256) gemm1_rope(const unsigned short* __restrict__ xb,
                                                  const unsigned short* __restrict__ Wt,
                                                  const float* __restrict__ bias,
                                                  const float2* __restrict__ tab,
                                                  unsigned short* __restrict__ qws,
                                                  unsigned short* __restrict__ kws) {
    // 36864 B: K-loop staging uses first 16384; epilogue restages 2x(128x144B)
    __shared__ __align__(16) char smem[36864];
    unsigned short* Alds = (unsigned short*)smem;            // 128 x 32 bf16
    unsigned short* Blds = (unsigned short*)(smem + 8192);   // 128 x 32 bf16

    const int bx = blockIdx.x;              // tile_m * 12 + h
    const int tile_m = bx / HEADS;
    const int h = bx - tile_m * HEADS;
    const int m0 = tile_m * 128;
    const int n0 = h * 128;

    const int t = threadIdx.x;
    const int w = t >> 6;
    const int lane = t & 63;
    const int wm = w >> 1;          // 0..1 row half
    const int wn = w & 1;           // 0 -> q half, 1 -> k half
    const int c16 = lane & 15;
    const int quad = lane >> 4;

    const int row0 = w * 32 + (lane >> 2);
    const int celem = (lane & 3) * 8;
    const unsigned short* ga0 = xb + (size_t)(m0 + row0) * HD + celem;
    const unsigned short* ga1 = xb + (size_t)(m0 + row0 + 16) * HD + celem;
    const unsigned short* gb0 = Wt + (size_t)(n0 + row0) * HD + celem;
    const unsigned short* gb1 = Wt + (size_t)(n0 + row0 + 16) * HD + celem;
    unsigned short* la0 = Alds + row0 * 32 + celem;
    unsigned short* la1 = Alds + (row0 + 16) * 32 + celem;
    unsigned short* lb0 = Blds + row0 * 32 + celem;
    unsigned short* lb1 = Blds + (row0 + 16) * 32 + celem;

    f32x4 acc[4][4];
#pragma unroll
    for (int i = 0; i < 4; ++i)
#pragma unroll
        for (int j = 0; j < 4; ++j) acc[i][j] = (f32x4){0.f, 0.f, 0.f, 0.f};

    for (int kt = 0; kt < HD; kt += 32) {
        gl_lds16(ga0 + kt, la0);
        gl_lds16(ga1 + kt, la1);
        gl_lds16(gb0 + kt, lb0);
        gl_lds16(gb1 + kt, lb1);
        __syncthreads();   // drains vmcnt (global_load_lds) before reads

        bf16x8 af[4], bfr[4];
#pragma unroll
        for (int mi = 0; mi < 4; ++mi)
            af[mi] = *(const bf16x8*)((char*)Alds + (wm * 64 + mi * 16 + c16) * 64 + quad * 16);
#pragma unroll
        for (int ni = 0; ni < 4; ++ni)
            bfr[ni] = *(const bf16x8*)((char*)Blds + (wn * 64 + ni * 16 + c16) * 64 + quad * 16);
#pragma unroll
        for (int mi = 0; mi < 4; ++mi)
#pragma unroll
            for (int ni = 0; ni < 4; ++ni)
                acc[mi][ni] = __builtin_amdgcn_mfma_f32_16x16x32_bf16(af[mi], bfr[ni], acc[mi][ni], 0, 0, 0);
        __syncthreads();   // before next iter overwrites LDS
    }

    // ---- epilogue: bias + RoPE + pack to LDS tile, then coalesced store ----
    float bv[4];
#pragma unroll
    for (int ni = 0; ni < 4; ++ni) bv[ni] = bias[n0 + wn * 64 + ni * 16 + c16];

    const int bb = m0 >> 9;                 // batch (tiles never cross b: 128|512)
    const int sbase = m0 & (SEQ - 1);
    const float2* tb = tab + sbase * 32;
    // stage: wn==0 -> q tile at smem[0], wn==1 -> k tile at smem[18432]
    char* stage = smem + wn * 18432;        // 128 rows x 144 B (72 bf16), swizzled
    const int odd = lane & 1;

#pragma unroll
    for (int mi = 0; mi < 4; ++mi) {
#pragma unroll
        for (int ni = 0; ni < 4; ++ni) {
            const int d = ni * 16 + c16;     // 0..63 within head
            const int fi = d >> 1;
#pragma unroll
            for (int r = 0; r < 4; ++r) {
                const int srow = wm * 64 + mi * 16 + quad * 4 + r;
                float v = acc[mi][ni][r] + bv[ni];
                float p = __shfl_xor(v, 1, 64);      // RoPE pair partner (same srow, d^1)
                float ve = odd ? p : v;              // even-d element of pair
                float vo = odd ? v : p;              // odd-d element of pair
                float2 sc = tb[srow * 32 + fi];
                float oe = ve * sc.y - vo * sc.x;
                float oo = vo * sc.y + ve * sc.x;
                unsigned pk;
                asm("v_cvt_pk_bf16_f32 %0, %1, %2" : "=v"(pk) : "v"(oe), "v"(oo));
                if (!odd) {
                    // byte offset with XOR swizzle to spread quads across banks
                    int boff = srow * 144 + ((fi * 4) ^ ((srow & 7) << 4));
                    *(unsigned*)(stage + boff) = pk;
                }
            }
        }
    }
    __syncthreads();

    // coalesced store: 2 tiles x 128 rows x 8 x 16B chunks = 2048 chunks
    const size_t gq = ((size_t)(bb * HEADS + h) * SEQ + sbase) * HEAD_SIZE;
#pragma unroll
    for (int it = 0; it < 8; ++it) {
        int chunk = it * 256 + t;
        int tile = chunk >> 10;          // 0: q, 1: k
        int c = chunk & 1023;
        int row = c >> 3;
        int cc = c & 7;                  // 16B chunk within 128B row
        uint4 v = *(const uint4*)(smem + tile * 18432 + row * 144 + ((cc * 16) ^ ((row & 7) << 4)));
        unsigned short* dstb = tile ? kws : qws;
        *(uint4*)&dstb[gq + row * 64 + cc * 8] = v;
    }
}

// ---------------------------------------------------------------------------
// Kernel 3: logits[b,h,m,n] = (q[bh,m,:].k[bh,n,:] - (pad+tril)*INF) / 8
// SWAPPED-operand MFMA: D = mfma(k_frag, q_frag) puts n on the register axis
// (n = quad*4 + reg, m = c16) -> one float4 store per (mi,ni): 16 dwordx4
// stores/thread (1 KB/instr) instead of 64 scalar dword stores.
// ---------------------------------------------------------------------------
__global__ void __launch_bounds__(256) gemm2_mask(const unsigned short* __restrict__ qws,
                                                  const unsigned short* __restrict__ kws,
                                                  const int* __restrict__ am,
                                                  float* __restrict__ out) {
    __shared__ __align__(16) unsigned short qlds[128 * 72];
    __shared__ __align__(16) unsigned short klds[128 * 72];
    const int bh = blockIdx.y;
    const int b = bh / HEADS;
    const int tm = (blockIdx.x >> 2) * 128;
    const int tn = (blockIdx.x & 3) * 128;
    const int t = threadIdx.x;
    const int w = t >> 6, lane = t & 63;
    const int wm = w >> 1, wn = w & 1;
    const int c16 = lane & 15, quad = lane >> 4;

    {
        const int sr = t >> 1;
        const int sc = (t & 1) * 32;  // elems
        const uint4* src = (const uint4*)(qws + ((size_t)bh * SEQ + tm + sr) * HEAD_SIZE + sc);
        uint4* dst = (uint4*)((char*)qlds + sr * 144 + sc * 2);
        dst[0] = src[0]; dst[1] = src[1]; dst[2] = src[2]; dst[3] = src[3];
        const uint4* src2 = (const uint4*)(kws + ((size_t)bh * SEQ + tn + sr) * HEAD_SIZE + sc);
        uint4* dst2 = (uint4*)((char*)klds + sr * 144 + sc * 2);
        dst2[0] = src2[0]; dst2[1] = src2[1]; dst2[2] = src2[2]; dst2[3] = src2[3];
    }
    __syncthreads();

    f32x4 acc[4][4];
#pragma unroll
    for (int i = 0; i < 4; ++i)
#pragma unroll
        for (int j = 0; j < 4; ++j) acc[i][j] = (f32x4){0.f, 0.f, 0.f, 0.f};

#pragma unroll
    for (int ks = 0; ks < 2; ++ks) {
        bf16x8 af[4], bfr[4];
#pragma unroll
        for (int mi = 0; mi < 4; ++mi)
            af[mi] = *(const bf16x8*)((char*)qlds + (wm * 64 + mi * 16 + c16) * 144 + ks * 64 + quad * 16);
#pragma unroll
        for (int ni = 0; ni < 4; ++ni)
            bfr[ni] = *(const bf16x8*)((char*)klds + (wn * 64 + ni * 16 + c16) * 144 + ks * 64 + quad * 16);
        // SWAPPED: A-operand = k rows (n), B-operand = q rows (m)
        // -> D[n][m]: row n = quad*4 + reg, col m = c16
#pragma unroll
        for (int mi = 0; mi < 4; ++mi)
#pragma unroll
            for (int ni = 0; ni < 4; ++ni)
                acc[mi][ni] = __builtin_amdgcn_mfma_f32_16x16x32_bf16(bfr[ni], af[mi], acc[mi][ni], 0, 0, 0);
    }

    const int* amb = am + b * SEQ;
    float ammv[4];
#pragma unroll
    for (int mi = 0; mi < 4; ++mi) ammv[mi] = (float)amb[tm + wm * 64 + mi * 16 + c16];

#pragma unroll
    for (int ni = 0; ni < 4; ++ni) {
        const int nb = tn + wn * 64 + ni * 16 + quad * 4;   // 4-aligned
        const int4 a4 = *(const int4*)&amb[nb];
        const float an0 = (float)a4.x, an1 = (float)a4.y, an2 = (float)a4.z, an3 = (float)a4.w;
#pragma unroll
        for (int mi = 0; mi < 4; ++mi) {
            const int m = tm + wm * 64 + mi * 16 + c16;
            const float amm = ammv[mi];
            float4 o;
            o.x = (acc[mi][ni][0] - ((1.0f - amm * an0) + ((m > nb + 0) ? 1.0f : 0.0f)) * INF_VAL) * 0.125f;
            o.y = (acc[mi][ni][1] - ((1.0f - amm * an1) + ((m > nb + 1) ? 1.0f : 0.0f)) * INF_VAL) * 0.125f;
            o.z = (acc[mi][ni][2] - ((1.0f - amm * an2) + ((m > nb + 2) ? 1.0f : 0.0f)) * INF_VAL) * 0.125f;
            o.w = (acc[mi][ni][3] - ((1.0f - amm * an3) + ((m > nb + 3) ? 1.0f : 0.0f)) * INF_VAL) * 0.125f;
            *(float4*)&out[((size_t)bh * SEQ + m) * SEQ + nb] = o;
        }
    }
}

extern "C" void kernel_launch(void* const* d_in, const int* in_sizes, int n_in,
                              void* d_out, int out_size, void* d_ws, size_t ws_size,
                              hipStream_t stream) {
    (void)in_sizes; (void)n_in; (void)out_size; (void)ws_size;
    const float* x = (const float*)d_in[0];
    const float* W = (const float*)d_in[1];
    const float* bias = (const float*)d_in[2];
    const int* am = (const int*)d_in[3];
    float* out = (float*)d_out;

    // workspace layout
    unsigned short* Wt  = (unsigned short*)d_ws;                                   // 3 MiB
    unsigned short* qws = (unsigned short*)((char*)d_ws + 3145728);                // 24 MiB
    unsigned short* kws = (unsigned short*)((char*)d_ws + 3145728 + 25165824);     // 24 MiB
    unsigned short* xb  = (unsigned short*)((char*)d_ws + 3145728 + 2 * 25165824); // 32 MiB
    float2* tab = (float2*)((char*)d_ws + 3145728 + 2 * 25165824 + 33554432);      // 128 KiB

    hipLaunchKernelGGL(convert_x, dim3(8192), dim3(256), 0, stream, x, xb);
    hipLaunchKernelGGL(transpose_cast_w, dim3(384), dim3(256), 0, stream, W, Wt);
    hipLaunchKernelGGL(rope_table, dim3(64), dim3(256), 0, stream, tab);
    hipLaunchKernelGGL(gemm1_rope, dim3(128 * HEADS), dim3(256), 0, stream, xb, Wt, bias, tab, qws, kws);
    hipLaunchKernelGGL(gemm2_mask, dim3(16, 32 * HEADS), dim3(256), 0, stream, qws, kws, am, out);
}

// Round 3
// 568.270 us; speedup vs baseline: 1.0307x; 1.0307x over previous
//
#include <hip/hip_runtime.h>
#include <hip/hip_bf16.h>
#include <cstdint>

#define HEADS 12
#define HEAD_SIZE 64
#define SEQ 512
#define HD 1024
#define NPROJ 1536   // HEADS * 2 * HEAD_SIZE
#define INF_VAL 1e13f

typedef __attribute__((ext_vector_type(8))) __bf16 bf16x8;
typedef __attribute__((ext_vector_type(4))) float f32x4;

__device__ __forceinline__ unsigned short f2bf(float f) {
    unsigned u = __float_as_uint(f);
    u += 0x7fffu + ((u >> 16) & 1u);   // RNE
    return (unsigned short)(u >> 16);
}

// async global -> LDS, 16B per lane, lane-ordered contiguous LDS destination
__device__ __forceinline__ void gl_lds16(const unsigned short* g, unsigned short* l) {
    __builtin_amdgcn_global_load_lds(
        (const __attribute__((address_space(1))) unsigned int*)g,
        (__attribute__((address_space(3))) unsigned int*)l, 16, 0, 0);
}

// ---------------------------------------------------------------------------
// Kernel 0: x (f32) -> xb (bf16), flat cast. 16,777,216 elems, 8 per thread.
// ---------------------------------------------------------------------------
__global__ void __launch_bounds__(256) convert_x(const float* __restrict__ x,
                                                 unsigned short* __restrict__ xb) {
    const int i = blockIdx.x * 256 + threadIdx.x;
    const float4* src = (const float4*)x;
    float4 v0 = src[i * 2 + 0];
    float4 v1 = src[i * 2 + 1];
    uint4 p;
    p.x = f2bf(v0.x) | ((unsigned)f2bf(v0.y) << 16);
    p.y = f2bf(v0.z) | ((unsigned)f2bf(v0.w) << 16);
    p.z = f2bf(v1.x) | ((unsigned)f2bf(v1.y) << 16);
    p.w = f2bf(v1.z) | ((unsigned)f2bf(v1.w) << 16);
    ((uint4*)xb)[i] = p;
}

// ---------------------------------------------------------------------------
// Kernel 1: W (1024 x 1536 f32, row-major) -> Wt (1536 x 1024 bf16)
// ---------------------------------------------------------------------------
__global__ void __launch_bounds__(256) transpose_cast_w(const float* __restrict__ W,
                                                        unsigned short* __restrict__ Wt) {
    __shared__ unsigned short tile[64][65];
    const int bx = blockIdx.x;
    const int k0 = (bx & 15) * 64;   // 16 k-tiles
    const int n0 = (bx >> 4) * 64;   // 24 n-tiles
    const int t = threadIdx.x;
    const int tr = t >> 4;           // 0..15
    const int tc = (t & 15) * 4;     // 0..60
#pragma unroll
    for (int i = 0; i < 4; ++i) {
        int kk = tr + i * 16;
        float4 v = *(const float4*)&W[(size_t)(k0 + kk) * NPROJ + n0 + tc];
        tile[kk][tc + 0] = f2bf(v.x);
        tile[kk][tc + 1] = f2bf(v.y);
        tile[kk][tc + 2] = f2bf(v.z);
        tile[kk][tc + 3] = f2bf(v.w);
    }
    __syncthreads();
#pragma unroll
    for (int i = 0; i < 4; ++i) {
        int nn = tr + i * 16;
        ushort4 o;
        o.x = tile[tc + 0][nn];
        o.y = tile[tc + 1][nn];
        o.z = tile[tc + 2][nn];
        o.w = tile[tc + 3][nn];
        *(ushort4*)&Wt[(size_t)(n0 + nn) * HD + k0 + tc] = o;
    }
}

// ---------------------------------------------------------------------------
// Kernel 1b: RoPE sin/cos table -> global, 512 positions x 32 freqs, f32x2.
// 128 KB, L2-resident for gemm1's reads.
// ---------------------------------------------------------------------------
__global__ void __launch_bounds__(256) rope_table(float2* __restrict__ tab) {
    const int e = blockIdx.x * 256 + threadIdx.x;   // 0..16383
    const int srow = e >> 5;
    const int fi = e & 31;
    float invf = __expf(-(float)fi * (0.03125f * 9.210340371976184f)); // 10000^(-fi/32)
    float theta = (float)srow * invf;
    float sv, cv;
    __sincosf(theta, &sv, &cv);
    tab[e] = make_float2(sv, cv);
}

// ---------------------------------------------------------------------------
// Kernel 2: proj = xb @ Wt^T + b, fused RoPE, writes q/k bf16 in (B,H,S,D).
// m97 K-loop (128x128 tile, BK=32, 32KB LDS -> 5 blocks/CU LDS-cap).
// Lean epilogue: global RoPE table (no per-block sincos), pair-packed
// dword stores via v_cvt_pk_bf16_f32 (no LDS restage, no extra barrier).
// ---------------------------------------------------------------------------
__global__ void __launch_bounds__(256) gemm1_rope(const unsigned short* __restrict__ xb,
                                                  const unsigned short* __restrict__ Wt,
                                                  const float* __restrict__ bias,
                                                  const float2* __restrict__ tab,
                                                  unsigned short* __restrict__ qws,
                                                  unsigned short* __restrict__ kws) {
    __shared__ __align__(16) char smem[32768];
    unsigned short* Alds = (unsigned short*)smem;            // 128 x 32 bf16
    unsigned short* Blds = (unsigned short*)(smem + 8192);   // 128 x 32 bf16

    const int bx = blockIdx.x;              // tile_m * 12 + h
    const int tile_m = bx / HEADS;
    const int h = bx - tile_m * HEADS;
    const int m0 = tile_m * 128;
    const int n0 = h * 128;

    const int t = threadIdx.x;
    const int w = t >> 6;
    const int lane = t & 63;
    const int wm = w >> 1;          // 0..1 row half
    const int wn = w & 1;           // 0 -> q half, 1 -> k half
    const int c16 = lane & 15;
    const int quad = lane >> 4;

    const int row0 = w * 32 + (lane >> 2);
    const int celem = (lane & 3) * 8;
    const unsigned short* ga0 = xb + (size_t)(m0 + row0) * HD + celem;
    const unsigned short* ga1 = xb + (size_t)(m0 + row0 + 16) * HD + celem;
    const unsigned short* gb0 = Wt + (size_t)(n0 + row0) * HD + celem;
    const unsigned short* gb1 = Wt + (size_t)(n0 + row0 + 16) * HD + celem;
    unsigned short* la0 = Alds + row0 * 32 + celem;
    unsigned short* la1 = Alds + (row0 + 16) * 32 + celem;
    unsigned short* lb0 = Blds + row0 * 32 + celem;
    unsigned short* lb1 = Blds + (row0 + 16) * 32 + celem;

    f32x4 acc[4][4];
#pragma unroll
    for (int i = 0; i < 4; ++i)
#pragma unroll
        for (int j = 0; j < 4; ++j) acc[i][j] = (f32x4){0.f, 0.f, 0.f, 0.f};

    for (int kt = 0; kt < HD; kt += 32) {
        gl_lds16(ga0 + kt, la0);
        gl_lds16(ga1 + kt, la1);
        gl_lds16(gb0 + kt, lb0);
        gl_lds16(gb1 + kt, lb1);
        __syncthreads();   // drains vmcnt (global_load_lds) before reads

        bf16x8 af[4], bfr[4];
#pragma unroll
        for (int mi = 0; mi < 4; ++mi)
            af[mi] = *(const bf16x8*)((char*)Alds + (wm * 64 + mi * 16 + c16) * 64 + quad * 16);
#pragma unroll
        for (int ni = 0; ni < 4; ++ni)
            bfr[ni] = *(const bf16x8*)((char*)Blds + (wn * 64 + ni * 16 + c16) * 64 + quad * 16);
#pragma unroll
        for (int mi = 0; mi < 4; ++mi)
#pragma unroll
            for (int ni = 0; ni < 4; ++ni)
                acc[mi][ni] = __builtin_amdgcn_mfma_f32_16x16x32_bf16(af[mi], bfr[ni], acc[mi][ni], 0, 0, 0);
        __syncthreads();   // before next iter overwrites LDS
    }

    // ---- lean epilogue: bias + RoPE (table) + paired dword stores ----
    float bv[4];
#pragma unroll
    for (int ni = 0; ni < 4; ++ni) bv[ni] = bias[n0 + wn * 64 + ni * 16 + c16];

    const int bb = m0 >> 9;                 // batch (tiles never cross b: 128|512)
    const int sbase = m0 & (SEQ - 1);
    const int odd = c16 & 1;
    const float sgn = odd ? 1.f : -1.f;
    unsigned short* outp = wn ? kws : qws;
    const size_t obase = ((size_t)(bb * HEADS + h) * SEQ + sbase) * HEAD_SIZE;

#pragma unroll
    for (int mi = 0; mi < 4; ++mi) {
#pragma unroll
        for (int ni = 0; ni < 4; ++ni) {
            const int d = ni * 16 + c16;     // 0..63 within head
            const int fi = d >> 1;
#pragma unroll
            for (int r = 0; r < 4; ++r) {
                const int srow = wm * 64 + mi * 16 + quad * 4 + r;
                float v = acc[mi][ni][r] + bv[ni];
                float p = __shfl_xor(v, 1, 64);          // RoPE pair partner (d^1)
                float2 sc = tab[(sbase + srow) * 32 + fi];
                float o = v * sc.y + sgn * p * sc.x;     // even: v*c - p*s ; odd: v*c + p*s
                float o2 = __shfl_xor(o, 1, 64);         // partner's output
                if (!odd) {
                    unsigned pk;
                    asm("v_cvt_pk_bf16_f32 %0, %1, %2" : "=v"(pk) : "v"(o), "v"(o2));
                    *(unsigned*)&outp[obase + (size_t)srow * HEAD_SIZE + d] = pk;
                }
            }
        }
    }
}

// ---------------------------------------------------------------------------
// Kernel 3: logits[b,h,m,n] = (q[bh,m,:].k[bh,n,:] - (pad+tril)*INF) / 8
// NO LDS, NO barrier: MFMA fragments loaded straight from global (q/k rows
// are 128B contiguous; fragment = 16B at row*64 + ks*32 + quad*8 -> a
// 16-rows x 64B pattern, L2-served; each bh tile is 32KB, reused 4x).
// Swapped-operand MFMA keeps the float4-store layout (n on register axis).
// Nontemporal out stores: 402 MB streams past L2, keeps q/k resident.
// ---------------------------------------------------------------------------
__global__ void __launch_bounds__(256) gemm2_mask(const unsigned short* __restrict__ qws,
                                                  const unsigned short* __restrict__ kws,
                                                  const int* __restrict__ am,
                                                  float* __restrict__ out) {
    const int bh = blockIdx.y;
    const int b = bh / HEADS;
    const int tm = (blockIdx.x >> 2) * 128;
    const int tn = (blockIdx.x & 3) * 128;
    const int t = threadIdx.x;
    const int w = t >> 6, lane = t & 63;
    const int wm = w >> 1, wn = w & 1;
    const int c16 = lane & 15, quad = lane >> 4;

    const unsigned short* qp = qws + (size_t)bh * SEQ * HEAD_SIZE;
    const unsigned short* kp = kws + (size_t)bh * SEQ * HEAD_SIZE;

    f32x4 acc[4][4];
#pragma unroll
    for (int i = 0; i < 4; ++i)
#pragma unroll
        for (int j = 0; j < 4; ++j) acc[i][j] = (f32x4){0.f, 0.f, 0.f, 0.f};

#pragma unroll
    for (int ks = 0; ks < 2; ++ks) {
        bf16x8 af[4], bfr[4];
#pragma unroll
        for (int mi = 0; mi < 4; ++mi)
            af[mi] = *(const bf16x8*)(qp + (size_t)(tm + wm * 64 + mi * 16 + c16) * HEAD_SIZE
                                         + ks * 32 + quad * 8);
#pragma unroll
        for (int ni = 0; ni < 4; ++ni)
            bfr[ni] = *(const bf16x8*)(kp + (size_t)(tn + wn * 64 + ni * 16 + c16) * HEAD_SIZE
                                          + ks * 32 + quad * 8);
        // SWAPPED: A-operand = k rows (n), B-operand = q rows (m)
        // -> D[n][m]: row n = quad*4 + reg, col m = c16
#pragma unroll
        for (int mi = 0; mi < 4; ++mi)
#pragma unroll
            for (int ni = 0; ni < 4; ++ni)
                acc[mi][ni] = __builtin_amdgcn_mfma_f32_16x16x32_bf16(bfr[ni], af[mi], acc[mi][ni], 0, 0, 0);
    }

    const int* amb = am + b * SEQ;
    float ammv[4];
#pragma unroll
    for (int mi = 0; mi < 4; ++mi) ammv[mi] = (float)amb[tm + wm * 64 + mi * 16 + c16];

#pragma unroll
    for (int ni = 0; ni < 4; ++ni) {
        const int nb = tn + wn * 64 + ni * 16 + quad * 4;   // 4-aligned
        const int4 a4 = *(const int4*)&amb[nb];
        const float an0 = (float)a4.x, an1 = (float)a4.y, an2 = (float)a4.z, an3 = (float)a4.w;
#pragma unroll
        for (int mi = 0; mi < 4; ++mi) {
            const int m = tm + wm * 64 + mi * 16 + c16;
            const float amm = ammv[mi];
            f32x4 o;
            o[0] = (acc[mi][ni][0] - ((1.0f - amm * an0) + ((m > nb + 0) ? 1.0f : 0.0f)) * INF_VAL) * 0.125f;
            o[1] = (acc[mi][ni][1] - ((1.0f - amm * an1) + ((m > nb + 1) ? 1.0f : 0.0f)) * INF_VAL) * 0.125f;
            o[2] = (acc[mi][ni][2] - ((1.0f - amm * an2) + ((m > nb + 2) ? 1.0f : 0.0f)) * INF_VAL) * 0.125f;
            o[3] = (acc[mi][ni][3] - ((1.0f - amm * an3) + ((m > nb + 3) ? 1.0f : 0.0f)) * INF_VAL) * 0.125f;
            __builtin_nontemporal_store(o, (f32x4*)&out[((size_t)bh * SEQ + m) * SEQ + nb]);
        }
    }
}

extern "C" void kernel_launch(void* const* d_in, const int* in_sizes, int n_in,
                              void* d_out, int out_size, void* d_ws, size_t ws_size,
                              hipStream_t stream) {
    (void)in_sizes; (void)n_in; (void)out_size; (void)ws_size;
    const float* x = (const float*)d_in[0];
    const float* W = (const float*)d_in[1];
    const float* bias = (const float*)d_in[2];
    const int* am = (const int*)d_in[3];
    float* out = (float*)d_out;

    // workspace layout
    unsigned short* Wt  = (unsigned short*)d_ws;                                   // 3 MiB
    unsigned short* qws = (unsigned short*)((char*)d_ws + 3145728);                // 24 MiB
    unsigned short* kws = (unsigned short*)((char*)d_ws + 3145728 + 25165824);     // 24 MiB
    unsigned short* xb  = (unsigned short*)((char*)d_ws + 3145728 + 2 * 25165824); // 32 MiB
    float2* tab = (float2*)((char*)d_ws + 3145728 + 2 * 25165824 + 33554432);      // 128 KiB

    hipLaunchKernelGGL(convert_x, dim3(8192), dim3(256), 0, stream, x, xb);
    hipLaunchKernelGGL(transpose_cast_w, dim3(384), dim3(256), 0, stream, W, Wt);
    hipLaunchKernelGGL(rope_table, dim3(64), dim3(256), 0, stream, tab);
    hipLaunchKernelGGL(gemm1_rope, dim3(128 * HEADS), dim3(256), 0, stream, xb, Wt, bias, tab, qws, kws);
    hipLaunchKernelGGL(gemm2_mask, dim3(16, 32 * HEADS), dim3(256), 0, stream, qws, kws, am, out);
}